// Round 1
// baseline (3586.371 us; speedup 1.0000x reference)
//
#include <hip/hip_runtime.h>
#include <cstddef>

// LocalGOCorrOpt on MI355X — round 1: fp32, fused per-iteration kernel.
// Layouts:
//   f / out : NCHW fp32 (16,256,64,64)
//   rpad(ws): [b][c4][row 0..71][col 0..71][4ch]  zero-padded by 4, channel-quads
//             -> every correlation read is one aligned global_load_dwordx4
//   gbuf(ws): [b][c4][y][x][4ch]  per-pixel fgrad spill (row-local, no races)
// ws floats: [0..242] target/vp/wm per-d, [243] reg_weight, [244] step, then gbuf, then rpad.

#define FPL 4096   // 64*64 floats per f channel-plane
#define RPQ 20736  // 72*72*4 floats per rpad c4-plane
#define GPQ 16384  // 64*64*4 floats per gbuf c4-plane

// ---------------- constants kernel ----------------
__global__ void k_consts(const float* lsl, const float* freg, const float* lw,
                         const float* sw, const float* mw, float* ws) {
  int t = threadIdx.x;
  if (t < 81) {
    int dy = t / 9, dx = t % 9;
    float ky = (float)(dy - 4), kx = (float)(dx - 4);
    float dist = sqrtf(ky * ky + kx * kx);
    float tg = 0.f, vp = 0.f, z = 0.f;
    for (int k = 0; k < 10; ++k) {
      float bd = 2.f * dist - (float)k;               // dist/0.5 - k
      float bin = (k < 9) ? fmaxf(1.f - fabsf(bd), 0.f)
                          : fminf(fmaxf(1.f + bd, 0.f), 1.f);
      tg += lw[k] * bin; vp += sw[k] * bin; z += mw[k] * bin;
    }
    ws[t] = tg;                      // target_map
    ws[81 + t] = vp;                 // v_plus
    ws[162 + t] = 1.f / (1.f + expf(-z));  // weight_m (sigmoid)
  } else if (t == 81) {
    float fr = freg[0];
    ws[243] = fmaxf(fr * fr, 1e-10f) * (1.f / 65536.f);  // reg_weight
  } else if (t == 82) {
    ws[244] = expf(lsl[0]);          // step_length
  }
}

// ---------------- r repack: NCHW -> padded channel-quad ----------------
__global__ void k_pad(const float* __restrict__ r, float* __restrict__ rp) {
  size_t i = (size_t)blockIdx.x * 256 + threadIdx.x;
  const size_t N = (size_t)16 * 64 * 72 * 72 * 4;
  if (i >= N) return;
  int j = (int)(i & 3);
  size_t qi = i >> 2;
  int col = (int)(qi % 72); size_t t1 = qi / 72;
  int row = (int)(t1 % 72); size_t t2 = t1 / 72;
  int c4 = (int)(t2 % 64);  int b  = (int)(t2 / 64);
  int yy = row - 4, xx = col - 4;
  float v = 0.f;
  if ((unsigned)yy < 64u && (unsigned)xx < 64u)
    v = r[(((size_t)b * 256 + (size_t)(c4 * 4 + j)) * 64 + yy) * 64 + xx];
  rp[i] = v;
}

// ---------------- fused single-iteration kernel (fast path) ----------------
// block = 64 threads = one image row; thread = one pixel; no LDS, no barriers.
__global__ __launch_bounds__(64, 1) void k_iterA(
    const float* fin, const float* __restrict__ rp,
    const float* __restrict__ cst, float* __restrict__ gbuf, float* fout) {
  const int b = blockIdx.x >> 6, y = blockIdx.x & 63;
  const int x = threadIdx.x;
  const float rw = cst[243], step = cst[244];

  const float* fbase = fin + (size_t)b * 256 * FPL + (size_t)y * 64 + x;
  // rpad base at (row=y, col=x): entry for (dy,dx) sits at +(dy*72+dx)*4 floats
  const float* rbase = rp + (size_t)b * 64 * RPQ + ((size_t)y * 72 + x) * 4;
  float* gb = gbuf + (size_t)b * 64 * GPQ + ((size_t)y * 64 + x) * 4;

  // ---- P1: scores s[d] = sum_c f[c] * R[c,d] ----
  float sacc[81];
#pragma unroll
  for (int d = 0; d < 81; ++d) sacc[d] = 0.f;
  for (int c4 = 0; c4 < 64; ++c4) {
    const float* fc = fbase + (size_t)c4 * 4 * FPL;
    float f0 = fc[0], f1 = fc[FPL], f2 = fc[2 * FPL], f3 = fc[3 * FPL];
    const float* rc = rbase + (size_t)c4 * RPQ;
#pragma unroll
    for (int dy = 0; dy < 9; ++dy) {
#pragma unroll
      for (int dx = 0; dx < 9; ++dx) {
        float4 rv = *(const float4*)(rc + (size_t)(dy * 72 + dx) * 4);
        float a = sacc[dy * 9 + dx];
        a = fmaf(f0, rv.x, a); a = fmaf(f1, rv.y, a);
        a = fmaf(f2, rv.z, a); a = fmaf(f3, rv.w, a);
        sacc[dy * 9 + dx] = a;
      }
    }
  }

  // ---- P2: mapped (in place) + sign masks for ga ----
  unsigned pm[3] = {0u, 0u, 0u}, nm[3] = {0u, 0u, 0u};
#pragma unroll
  for (int d = 0; d < 81; ++d) {
    float s = sacc[d];
    float tg = cst[d], vp = cst[81 + d], wm = cst[162 + d];
    float ga = vp * (s > 0.f ? 1.f : (s < 0.f ? wm : 0.5f * (1.f + wm)));
    sacc[d] = ga * fmaf(ga, s, -(vp * tg));   // mapped = ga*(ga*s - vp*target)
    pm[d / 27] |= (s > 0.f ? 1u : 0u) << (d % 27);
    nm[d / 27] |= (s < 0.f ? 1u : 0u) << (d % 27);
  }

  // ---- P3a: g = rw*f + R*mapped ; num = |g|^2 ; spill g to gbuf ----
  float n0 = 0.f, n1 = 0.f, n2 = 0.f, n3 = 0.f;
  for (int c4 = 0; c4 < 64; ++c4) {
    const float* fc = fbase + (size_t)c4 * 4 * FPL;
    const float* rc = rbase + (size_t)c4 * RPQ;
    float g0 = 0.f, g1 = 0.f, g2 = 0.f, g3 = 0.f;
#pragma unroll
    for (int dy = 0; dy < 9; ++dy) {
#pragma unroll
      for (int dx = 0; dx < 9; ++dx) {
        float4 rv = *(const float4*)(rc + (size_t)(dy * 72 + dx) * 4);
        float mv = sacc[dy * 9 + dx];
        g0 = fmaf(mv, rv.x, g0); g1 = fmaf(mv, rv.y, g1);
        g2 = fmaf(mv, rv.z, g2); g3 = fmaf(mv, rv.w, g3);
      }
    }
    g0 = fmaf(rw, fc[0], g0);       g1 = fmaf(rw, fc[FPL], g1);
    g2 = fmaf(rw, fc[2 * FPL], g2); g3 = fmaf(rw, fc[3 * FPL], g3);
    float4 g4; g4.x = g0; g4.y = g1; g4.z = g2; g4.w = g3;
    *(float4*)(gb + (size_t)c4 * GPQ) = g4;
    n0 = fmaf(g0, g0, n0); n1 = fmaf(g1, g1, n1);
    n2 = fmaf(g2, g2, n2); n3 = fmaf(g3, g3, n3);
  }
  float num = (n0 + n1) + (n2 + n3);

  // ---- P3b: t2[d] = sum_c g[c] * R[c,d] ----
  float t2[81];
#pragma unroll
  for (int d = 0; d < 81; ++d) t2[d] = 0.f;
  for (int c4 = 0; c4 < 64; ++c4) {
    const float* rc = rbase + (size_t)c4 * RPQ;
    float4 g4 = *(const float4*)(gb + (size_t)c4 * GPQ);
#pragma unroll
    for (int dy = 0; dy < 9; ++dy) {
#pragma unroll
      for (int dx = 0; dx < 9; ++dx) {
        float4 rv = *(const float4*)(rc + (size_t)(dy * 72 + dx) * 4);
        float a = t2[dy * 9 + dx];
        a = fmaf(g4.x, rv.x, a); a = fmaf(g4.y, rv.y, a);
        a = fmaf(g4.z, rv.z, a); a = fmaf(g4.w, rv.w, a);
        t2[dy * 9 + dx] = a;
      }
    }
  }

  // ---- P4: den, coef ----
  float den = 0.f;
#pragma unroll
  for (int d = 0; d < 81; ++d) {
    float vp = cst[81 + d], wm = cst[162 + d];
    unsigned p = (pm[d / 27] >> (d % 27)) & 1u;
    unsigned n = (nm[d / 27] >> (d % 27)) & 1u;
    float ga = vp * (p ? 1.f : (n ? wm : 0.5f * (1.f + wm)));
    float s2 = ga * t2[d];
    den = fmaf(s2, s2, den);
  }
  den = fmaxf(fmaf(rw, num, den), 1e-8f);
  float coef = step * num / den;

  // ---- P5: f_new = f - coef * g ----
  float* ob = fout + (size_t)b * 256 * FPL + (size_t)y * 64 + x;
  for (int c4 = 0; c4 < 64; ++c4) {
    const float* fc = fbase + (size_t)c4 * 4 * FPL;
    float4 g4 = *(const float4*)(gb + (size_t)c4 * GPQ);
    size_t o = (size_t)c4 * 4 * FPL;
    ob[o]           = fmaf(-coef, g4.x, fc[0]);
    ob[o + FPL]     = fmaf(-coef, g4.y, fc[FPL]);
    ob[o + 2 * FPL] = fmaf(-coef, g4.z, fc[2 * FPL]);
    ob[o + 3 * FPL] = fmaf(-coef, g4.w, fc[3 * FPL]);
  }
}

// ---------------- fallback: self-contained, no workspace needed ----------------
__device__ __forceinline__ void consts_d(int d, const float* lwr, const float* swr,
                                         const float* mwr, float& tg, float& vp,
                                         float& wm) {
  int dy = d / 9, dx = d % 9;
  float ky = (float)(dy - 4), kx = (float)(dx - 4);
  float dist = sqrtf(ky * ky + kx * kx);
  float t = 0.f, v = 0.f, z = 0.f;
#pragma unroll
  for (int k = 0; k < 10; ++k) {
    float bd = 2.f * dist - (float)k;
    float bin = (k < 9) ? fmaxf(1.f - fabsf(bd), 0.f)
                        : fminf(fmaxf(1.f + bd, 0.f), 1.f);
    t = fmaf(lwr[k], bin, t); v = fmaf(swr[k], bin, v); z = fmaf(mwr[k], bin, z);
  }
  tg = t; vp = v; wm = 1.f / (1.f + expf(-z));
}

__global__ __launch_bounds__(64, 1) void k_iterC(
    const float* fin, const float* __restrict__ r, const float* __restrict__ lsl,
    const float* __restrict__ freg, const float* __restrict__ lw,
    const float* __restrict__ sw, const float* __restrict__ mw, float* fout) {
  const int b = blockIdx.x >> 6, y = blockIdx.x & 63;
  const int x = threadIdx.x;
  float lwr[10], swr[10], mwr[10];
#pragma unroll
  for (int k = 0; k < 10; ++k) { lwr[k] = lw[k]; swr[k] = sw[k]; mwr[k] = mw[k]; }
  float fr = freg[0];
  const float rw = fmaxf(fr * fr, 1e-10f) * (1.f / 65536.f);
  const float step = expf(lsl[0]);
  const float* fb = fin + (size_t)b * 256 * FPL + (size_t)y * 64 + x;
  const float* rb = r + (size_t)b * 256 * FPL;

  float m[81];
#pragma unroll
  for (int d = 0; d < 81; ++d) m[d] = 0.f;
  for (int c = 0; c < 256; ++c) {           // P1: scores
    float fv = fb[(size_t)c * FPL];
    const float* rc = rb + (size_t)c * FPL;
#pragma unroll
    for (int dy = 0; dy < 9; ++dy) {
      int yy = y + dy - 4;
      if ((unsigned)yy < 64u) {
        const float* rrow = rc + yy * 64;
#pragma unroll
        for (int dx = 0; dx < 9; ++dx) {
          int xx = x + dx - 4;
          float rv = ((unsigned)xx < 64u) ? rrow[xx] : 0.f;
          m[dy * 9 + dx] = fmaf(fv, rv, m[dy * 9 + dx]);
        }
      }
    }
  }
  unsigned pm[3] = {0u, 0u, 0u}, nm[3] = {0u, 0u, 0u};
#pragma unroll
  for (int d = 0; d < 81; ++d) {            // P2
    float tg, vp, wm; consts_d(d, lwr, swr, mwr, tg, vp, wm);
    float s = m[d];
    float ga = vp * (s > 0.f ? 1.f : (s < 0.f ? wm : 0.5f * (1.f + wm)));
    m[d] = ga * fmaf(ga, s, -(vp * tg));
    pm[d / 27] |= (s > 0.f ? 1u : 0u) << (d % 27);
    nm[d / 27] |= (s < 0.f ? 1u : 0u) << (d % 27);
  }
  float t2[81];
#pragma unroll
  for (int d = 0; d < 81; ++d) t2[d] = 0.f;
  float num = 0.f;
  for (int c = 0; c < 256; ++c) {           // P3: g (recomputed later), num, t2
    float fv = fb[(size_t)c * FPL];
    const float* rc = rb + (size_t)c * FPL;
    float g0 = 0.f, g1 = 0.f, g2 = 0.f, g3 = 0.f;
#pragma unroll
    for (int dy = 0; dy < 9; ++dy) {
      int yy = y + dy - 4;
      if ((unsigned)yy < 64u) {
        const float* rrow = rc + yy * 64;
#pragma unroll
        for (int dx = 0; dx < 9; ++dx) {
          int xx = x + dx - 4;
          float rv = ((unsigned)xx < 64u) ? rrow[xx] : 0.f;
          if ((dy & 3) == 0)      g0 = fmaf(m[dy * 9 + dx], rv, g0);
          else if ((dy & 3) == 1) g1 = fmaf(m[dy * 9 + dx], rv, g1);
          else if ((dy & 3) == 2) g2 = fmaf(m[dy * 9 + dx], rv, g2);
          else                    g3 = fmaf(m[dy * 9 + dx], rv, g3);
        }
      }
    }
    float g = fmaf(rw, fv, (g0 + g1) + (g2 + g3));
    num = fmaf(g, g, num);
#pragma unroll
    for (int dy = 0; dy < 9; ++dy) {
      int yy = y + dy - 4;
      if ((unsigned)yy < 64u) {
        const float* rrow = rc + yy * 64;
#pragma unroll
        for (int dx = 0; dx < 9; ++dx) {
          int xx = x + dx - 4;
          float rv = ((unsigned)xx < 64u) ? rrow[xx] : 0.f;
          t2[dy * 9 + dx] = fmaf(g, rv, t2[dy * 9 + dx]);
        }
      }
    }
  }
  float den = 0.f;
#pragma unroll
  for (int d = 0; d < 81; ++d) {            // P4
    float tg, vp, wm; consts_d(d, lwr, swr, mwr, tg, vp, wm);
    (void)tg;
    unsigned p = (pm[d / 27] >> (d % 27)) & 1u;
    unsigned n = (nm[d / 27] >> (d % 27)) & 1u;
    float ga = vp * (p ? 1.f : (n ? wm : 0.5f * (1.f + wm)));
    float s2 = ga * t2[d];
    den = fmaf(s2, s2, den);
  }
  den = fmaxf(fmaf(rw, num, den), 1e-8f);
  float coef = step * num / den;
  float* ob = fout + (size_t)b * 256 * FPL + (size_t)y * 64 + x;
  for (int c = 0; c < 256; ++c) {           // P5: recompute g, update
    float fv = fb[(size_t)c * FPL];
    const float* rc = rb + (size_t)c * FPL;
    float g0 = 0.f, g1 = 0.f, g2 = 0.f, g3 = 0.f;
#pragma unroll
    for (int dy = 0; dy < 9; ++dy) {
      int yy = y + dy - 4;
      if ((unsigned)yy < 64u) {
        const float* rrow = rc + yy * 64;
#pragma unroll
        for (int dx = 0; dx < 9; ++dx) {
          int xx = x + dx - 4;
          float rv = ((unsigned)xx < 64u) ? rrow[xx] : 0.f;
          if ((dy & 3) == 0)      g0 = fmaf(m[dy * 9 + dx], rv, g0);
          else if ((dy & 3) == 1) g1 = fmaf(m[dy * 9 + dx], rv, g1);
          else if ((dy & 3) == 2) g2 = fmaf(m[dy * 9 + dx], rv, g2);
          else                    g3 = fmaf(m[dy * 9 + dx], rv, g3);
        }
      }
    }
    float g = fmaf(rw, fv, (g0 + g1) + (g2 + g3));
    ob[(size_t)c * FPL] = fmaf(-coef, g, fv);
  }
}

extern "C" void kernel_launch(void* const* d_in, const int* in_sizes, int n_in,
                              void* d_out, int out_size, void* d_ws, size_t ws_size,
                              hipStream_t stream) {
  (void)in_sizes; (void)n_in; (void)out_size;
  const float* f0 = (const float*)d_in[0];
  const float* r  = (const float*)d_in[1];
  const float* lsl = (const float*)d_in[2];
  const float* freg = (const float*)d_in[3];
  const float* lw = (const float*)d_in[4];
  const float* sw = (const float*)d_in[5];
  const float* mw = (const float*)d_in[6];
  float* out = (float*)d_out;

  const size_t CONSTS = 256;
  const size_t GSZ = (size_t)16 * 256 * 64 * 64;     // 16,777,216 floats
  const size_t RPSZ = (size_t)16 * 64 * 72 * 72 * 4; // 21,233,664 floats
  const size_t needed = (CONSTS + GSZ + RPSZ) * sizeof(float);

  if (ws_size >= needed) {
    float* ws = (float*)d_ws;
    float* gbuf = ws + CONSTS;
    float* rpad = gbuf + GSZ;
    k_consts<<<dim3(1), dim3(128), 0, stream>>>(lsl, freg, lw, sw, mw, ws);
    k_pad<<<dim3((unsigned)((RPSZ + 255) / 256)), dim3(256), 0, stream>>>(r, rpad);
    k_iterA<<<dim3(1024), dim3(64), 0, stream>>>(f0, rpad, ws, gbuf, out);
    k_iterA<<<dim3(1024), dim3(64), 0, stream>>>(out, rpad, ws, gbuf, out);
    k_iterA<<<dim3(1024), dim3(64), 0, stream>>>(out, rpad, ws, gbuf, out);
  } else {
    // workspace too small: fully self-contained fallback
    k_iterC<<<dim3(1024), dim3(64), 0, stream>>>(f0, r, lsl, freg, lw, sw, mw, out);
    k_iterC<<<dim3(1024), dim3(64), 0, stream>>>(out, r, lsl, freg, lw, sw, mw, out);
    k_iterC<<<dim3(1024), dim3(64), 0, stream>>>(out, r, lsl, freg, lw, sw, mw, out);
  }
}